// Round 12
// baseline (2922.367 us; speedup 1.0000x reference)
//
#include <hip/hip_runtime.h>
#include <hip/hip_bf16.h>
#include <math.h>

#define NNODES 100000
#define NREL 4
#define NEDGE 200000
#define NH 8
#define FDIM 512
#define NMB 782  // ceil(100000/128)

typedef float f4 __attribute__((ext_vector_type(4)));
typedef __bf16 bf16x8 __attribute__((ext_vector_type(8)));
typedef __bf16 bf16x4 __attribute__((ext_vector_type(4)));

__device__ __forceinline__ float eluf(float v) { return v > 0.f ? v : expm1f(v); }

// ---- f32 -> bf16 convert (count multiple of 1024) ----
__global__ void k_conv(const float* __restrict__ in, __bf16* __restrict__ outp) {
  int i = (blockIdx.x * 256 + threadIdx.x) * 4;
  f4 v = *(const f4*)(in + i);
  bf16x4 o = {(__bf16)v.x, (__bf16)v.y, (__bf16)v.z, (__bf16)v.w};
  *(bf16x4*)(outp + i) = o;
}

// ---- W [4,K,512] f32 -> Wt [4*512, K] bf16 (transposed), all relations ----
__global__ void k_transW(const float* __restrict__ W, __bf16* __restrict__ Wt, int K) {
  __shared__ float tile[32][33];
  int r = blockIdx.z;
  const float* Wr = W + (size_t)r * K * FDIM;
  __bf16* Wtr = Wt + (size_t)r * FDIM * K;
  int k0 = blockIdx.x * 32, n0 = blockIdx.y * 32;
  int tx = threadIdx.x, ty = threadIdx.y;
  for (int i = ty; i < 32; i += 8)
    tile[i][tx] = Wr[(size_t)(k0 + i) * FDIM + n0 + tx];
  __syncthreads();
  for (int i = ty; i < 32; i += 8)
    Wtr[(size_t)(n0 + i) * K + k0 + tx] = (__bf16)tile[tx][i];
}

// ---- bf16 MFMA GEMM, NO-LDS direct-from-global fragments, zero barriers.
//      128x128 tile, 4 waves (each 64x64 out), bijective XCD swizzle,
//      fused el/er epilogue (bf16). C[M,512] = A[M,K] * BT[512,K]^T ----
__global__ __launch_bounds__(256) void k_gemm(const __bf16* __restrict__ A,
                                              const __bf16* __restrict__ BT,
                                              __bf16* __restrict__ C,
                                              const float* __restrict__ al,
                                              const float* __restrict__ ar,
                                              __bf16* __restrict__ el,
                                              __bf16* __restrict__ er, int M, int K) {
  int t = threadIdx.x, l = t & 63, w = t >> 6;
  // bijective XCD-chunked swizzle (m204)
  int nwg = gridDim.x, q8 = nwg >> 3, r8 = nwg & 7;
  int xx = blockIdx.x & 7, loc = blockIdx.x >> 3;
  int swz = (xx < r8 ? xx * (q8 + 1) : r8 * (q8 + 1) + (xx - r8) * q8) + loc;
  int m0 = (swz >> 2) * 128, n0 = (swz & 3) * 128;
  int wm = (w >> 1) * 64, wn = (w & 1) * 64;
  f4 acc[4][4] = {};

  // fragment pointers: one 16B load = 16 rows x 64B fully-used cache lines
  const __bf16* pa[4];
  const __bf16* pb[4];
#pragma unroll
  for (int i = 0; i < 4; i++) {
    int row = m0 + wm + i * 16 + (l & 15);
    if (row >= M) row = M - 1;  // clamp: garbage rows never stored
    pa[i] = A + (size_t)row * K + (l >> 4) * 8;
    pb[i] = BT + (size_t)(n0 + wn + i * 16 + (l & 15)) * K + (l >> 4) * 8;
  }

  int nt = K >> 5;
#pragma unroll 2
  for (int kt = 0; kt < nt; kt++) {
    bf16x8 a[4], b[4];
#pragma unroll
    for (int i = 0; i < 4; i++) a[i] = *(const bf16x8*)(pa[i] + kt * 32);
#pragma unroll
    for (int j = 0; j < 4; j++) b[j] = *(const bf16x8*)(pb[j] + kt * 32);
#pragma unroll
    for (int i = 0; i < 4; i++)
#pragma unroll
      for (int j = 0; j < 4; j++)
        acc[i][j] = __builtin_amdgcn_mfma_f32_16x16x32_bf16(a[i], b[j], acc[i][j], 0, 0, 0);
  }

  // ---- C write (bf16, scalar stores — proven pattern) ----
  int cn = n0 + wn + (l & 15);
  int rbase = m0 + wm + (l >> 4) * 4;
#pragma unroll
  for (int i = 0; i < 4; i++)
#pragma unroll
    for (int q2 = 0; q2 < 4; q2++) {
      int row = rbase + i * 16 + q2;
      if (row < M) {
#pragma unroll
        for (int j = 0; j < 4; j++)
          C[(size_t)row * FDIM + cn + j * 16] = (__bf16)acc[i][j][q2];
      }
    }

  // ---- fused el/er (bf16 out): wave's 64-col slice == one head ----
  int h = (n0 + wn) >> 6;
  float av[4], bv[4];
#pragma unroll
  for (int j = 0; j < 4; j++) {
    av[j] = al[h * 64 + j * 16 + (l & 15)];
    bv[j] = ar[h * 64 + j * 16 + (l & 15)];
  }
#pragma unroll
  for (int i = 0; i < 4; i++)
#pragma unroll
    for (int q2 = 0; q2 < 4; q2++) {
      float se = acc[i][0][q2] * av[0] + acc[i][1][q2] * av[1] +
                 acc[i][2][q2] * av[2] + acc[i][3][q2] * av[3];
      float sr = acc[i][0][q2] * bv[0] + acc[i][1][q2] * bv[1] +
                 acc[i][2][q2] * bv[2] + acc[i][3][q2] * bv[3];
      se += __shfl_xor(se, 1); se += __shfl_xor(se, 2);
      se += __shfl_xor(se, 4); se += __shfl_xor(se, 8);
      sr += __shfl_xor(sr, 1); sr += __shfl_xor(sr, 2);
      sr += __shfl_xor(sr, 4); sr += __shfl_xor(sr, 8);
      if ((l & 15) == 0) {
        int row = rbase + i * 16 + q2;
        if (row < M) {
          el[row * NH + h] = (__bf16)se;
          er[row * NH + h] = (__bf16)sr;
        }
      }
    }
}

// ---- CSR build ----
__global__ void k_count(const int* __restrict__ dst, int* __restrict__ deg) {
  int e = blockIdx.x * 256 + threadIdx.x;
  int r = blockIdx.y;
  if (e < NEDGE) {
    int d = dst[(size_t)r * NEDGE + e];
    if ((unsigned)d < (unsigned)NNODES) atomicAdd(&deg[r * NNODES + d], 1);
  }
}

__global__ __launch_bounds__(256) void k_scan_a(const int* __restrict__ in, int* __restrict__ out,
                                                int* __restrict__ bsum, int n) {
  __shared__ int wsums[4];
  int t = threadIdx.x, lane = t & 63, w = t >> 6;
  int base = blockIdx.x * 1024 + t * 4;
  int v0 = base + 0 < n ? in[base + 0] : 0;
  int v1 = base + 1 < n ? in[base + 1] : 0;
  int v2 = base + 2 < n ? in[base + 2] : 0;
  int v3 = base + 3 < n ? in[base + 3] : 0;
  int tot = v0 + v1 + v2 + v3;
  int sc = tot;
#pragma unroll
  for (int off = 1; off < 64; off <<= 1) {
    int u = __shfl_up(sc, off);
    if (lane >= off) sc += u;
  }
  if (lane == 63) wsums[w] = sc;
  __syncthreads();
  int add = 0;
#pragma unroll
  for (int i = 0; i < 4; i++)
    if (i < w) add += wsums[i];
  int excl = add + sc - tot;
  if (base + 0 < n) out[base + 0] = excl;
  if (base + 1 < n) out[base + 1] = excl + v0;
  if (base + 2 < n) out[base + 2] = excl + v0 + v1;
  if (base + 3 < n) out[base + 3] = excl + v0 + v1 + v2;
  if (t == 255) bsum[blockIdx.x] = add + sc;
}

__global__ __launch_bounds__(256) void k_scan_b(int* __restrict__ bsum, int nb) {
  __shared__ int wsums[4];
  int t = threadIdx.x, lane = t & 63, w = t >> 6;
  int i0 = t * 2, i1 = t * 2 + 1;
  int v0 = i0 < nb ? bsum[i0] : 0;
  int v1 = i1 < nb ? bsum[i1] : 0;
  int tot = v0 + v1, sc = tot;
#pragma unroll
  for (int off = 1; off < 64; off <<= 1) {
    int u = __shfl_up(sc, off);
    if (lane >= off) sc += u;
  }
  if (lane == 63) wsums[w] = sc;
  __syncthreads();
  int add = 0;
#pragma unroll
  for (int i = 0; i < 4; i++)
    if (i < w) add += wsums[i];
  int excl = add + sc - tot;
  if (i0 < nb) bsum[i0] = excl;
  if (i1 < nb) bsum[i1] = excl + v0;
}

__global__ void k_scan_c(int* __restrict__ out, const int* __restrict__ bsum, int n) {
  int i = blockIdx.x * 256 + threadIdx.x;
  if (i < n) out[i] += bsum[i >> 10];
}

__global__ void k_scatter(const int* __restrict__ src, const int* __restrict__ dst,
                          const int* __restrict__ ptrf, int* __restrict__ cur,
                          int* __restrict__ csrc) {
  int e = blockIdx.x * 256 + threadIdx.x;
  int r = blockIdx.y;
  if (e >= NEDGE) return;
  int d = dst[(size_t)r * NEDGE + e];
  if ((unsigned)d >= (unsigned)NNODES) return;
  int slot = ptrf[r * NNODES + d] + atomicAdd(&cur[r * NNODES + d], 1);
  if ((unsigned)slot < (unsigned)(NREL * NEDGE))
    csrc[slot] = src[(size_t)r * NEDGE + e];
}

// ---- fused segment-softmax + aggregate + ELU, edge-unroll-2 dual accumulators;
//      writeMode=1: full write (replaces memset) ----
__global__ void k_agg(const __bf16* __restrict__ f, const __bf16* __restrict__ el,
                      const __bf16* __restrict__ er, const int* __restrict__ ptrf,
                      const int* __restrict__ deg, const int* __restrict__ csrc,
                      __bf16* __restrict__ accG, int writeMode) {
  int t = threadIdx.x;
  int l = t & 63;
  int d = blockIdx.x * 4 + (t >> 6);
  int h = l >> 3;
  int cnt = deg[d];
  float res[8] = {0.f, 0.f, 0.f, 0.f, 0.f, 0.f, 0.f, 0.f};
  if (cnt > 0) {
    int start = ptrf[d];
    if (start < 0) start = 0;
    if (start > NREL * NEDGE) start = NREL * NEDGE;
    if (cnt > NREL * NEDGE - start) cnt = NREL * NEDGE - start;
    float erh = (float)er[d * NH + h];
    float a0[8] = {0.f, 0.f, 0.f, 0.f, 0.f, 0.f, 0.f, 0.f};
    float a1[8] = {0.f, 0.f, 0.f, 0.f, 0.f, 0.f, 0.f, 0.f};
    float den = 0.f;
    int j = 0;
    for (; j + 1 < cnt; j += 2) {  // dual-issue: both gathers in flight together
      int s0 = csrc[start + j], s1 = csrc[start + j + 1];
      if ((unsigned)s0 >= (unsigned)NNODES) s0 = 0;
      if ((unsigned)s1 >= (unsigned)NNODES) s1 = 0;
      bf16x8 fv0 = *(const bf16x8*)(f + (size_t)s0 * FDIM + l * 8);
      bf16x8 fv1 = *(const bf16x8*)(f + (size_t)s1 * FDIM + l * 8);
      float e0 = (float)el[s0 * NH + h] + erh;
      float e1 = (float)el[s1 * NH + h] + erh;
      e0 = (e0 > 0.f) ? e0 : 0.2f * e0;
      e1 = (e1 > 0.f) ? e1 : 0.2f * e1;
      float ex0 = __expf(e0), ex1 = __expf(e1);
      den += ex0 + ex1;
#pragma unroll
      for (int i = 0; i < 8; i++) {
        a0[i] += ex0 * (float)fv0[i];
        a1[i] += ex1 * (float)fv1[i];
      }
    }
    if (j < cnt) {
      int s0 = csrc[start + j];
      if ((unsigned)s0 >= (unsigned)NNODES) s0 = 0;
      bf16x8 fv0 = *(const bf16x8*)(f + (size_t)s0 * FDIM + l * 8);
      float e0 = (float)el[s0 * NH + h] + erh;
      e0 = (e0 > 0.f) ? e0 : 0.2f * e0;
      float ex0 = __expf(e0);
      den += ex0;
#pragma unroll
      for (int i = 0; i < 8; i++) a0[i] += ex0 * (float)fv0[i];
    }
    float inv = 1.f / (den + 1e-9f);
#pragma unroll
    for (int i = 0; i < 8; i++) res[i] = eluf((a0[i] + a1[i]) * inv);
  } else if (!writeMode) {
    return;
  }
  __bf16* ap = accG + (size_t)d * FDIM + l * 8;
  bf16x8 o;
  if (writeMode) {
#pragma unroll
    for (int i = 0; i < 8; i++) o[i] = (__bf16)res[i];
  } else {
    bf16x8 cv = *(bf16x8*)ap;
#pragma unroll
    for (int i = 0; i < 8; i++) o[i] = (__bf16)((float)cv[i] + res[i]);
  }
  *(bf16x8*)ap = o;
}

// ---- layer-2 agg with FUSED head-mean (writes out[N,64] f32), edge-unroll-2 ----
__global__ void k_aggm(const __bf16* __restrict__ f, const __bf16* __restrict__ el,
                       const __bf16* __restrict__ er, const int* __restrict__ ptrf,
                       const int* __restrict__ deg, const int* __restrict__ csrc,
                       float* __restrict__ out, int writeMode) {
  int t = threadIdx.x;
  int l = t & 63;
  int d = blockIdx.x * 4 + (t >> 6);
  int h = l >> 3;
  int cnt = deg[d];
  float res[8] = {0.f, 0.f, 0.f, 0.f, 0.f, 0.f, 0.f, 0.f};
  if (cnt > 0) {
    int start = ptrf[d];
    if (start < 0) start = 0;
    if (start > NREL * NEDGE) start = NREL * NEDGE;
    if (cnt > NREL * NEDGE - start) cnt = NREL * NEDGE - start;
    float erh = (float)er[d * NH + h];
    float a0[8] = {0.f, 0.f, 0.f, 0.f, 0.f, 0.f, 0.f, 0.f};
    float a1[8] = {0.f, 0.f, 0.f, 0.f, 0.f, 0.f, 0.f, 0.f};
    float den = 0.f;
    int j = 0;
    for (; j + 1 < cnt; j += 2) {
      int s0 = csrc[start + j], s1 = csrc[start + j + 1];
      if ((unsigned)s0 >= (unsigned)NNODES) s0 = 0;
      if ((unsigned)s1 >= (unsigned)NNODES) s1 = 0;
      bf16x8 fv0 = *(const bf16x8*)(f + (size_t)s0 * FDIM + l * 8);
      bf16x8 fv1 = *(const bf16x8*)(f + (size_t)s1 * FDIM + l * 8);
      float e0 = (float)el[s0 * NH + h] + erh;
      float e1 = (float)el[s1 * NH + h] + erh;
      e0 = (e0 > 0.f) ? e0 : 0.2f * e0;
      e1 = (e1 > 0.f) ? e1 : 0.2f * e1;
      float ex0 = __expf(e0), ex1 = __expf(e1);
      den += ex0 + ex1;
#pragma unroll
      for (int i = 0; i < 8; i++) {
        a0[i] += ex0 * (float)fv0[i];
        a1[i] += ex1 * (float)fv1[i];
      }
    }
    if (j < cnt) {
      int s0 = csrc[start + j];
      if ((unsigned)s0 >= (unsigned)NNODES) s0 = 0;
      bf16x8 fv0 = *(const bf16x8*)(f + (size_t)s0 * FDIM + l * 8);
      float e0 = (float)el[s0 * NH + h] + erh;
      e0 = (e0 > 0.f) ? e0 : 0.2f * e0;
      float ex0 = __expf(e0);
      den += ex0;
#pragma unroll
      for (int i = 0; i < 8; i++) a0[i] += ex0 * (float)fv0[i];
    }
    float inv = 1.f / (den + 1e-9f);
#pragma unroll
    for (int i = 0; i < 8; i++) res[i] = eluf((a0[i] + a1[i]) * inv);
  }
  // cross-head sum: lanes with same (l&7) across the 8 head-groups
#pragma unroll
  for (int i = 0; i < 8; i++) {
    res[i] += __shfl_xor(res[i], 8);
    res[i] += __shfl_xor(res[i], 16);
    res[i] += __shfl_xor(res[i], 32);
  }
  if (l < 8) {
    float* op = out + (size_t)d * 64 + l * 8;
    f4 v0 = {res[0] * 0.125f, res[1] * 0.125f, res[2] * 0.125f, res[3] * 0.125f};
    f4 v1 = {res[4] * 0.125f, res[5] * 0.125f, res[6] * 0.125f, res[7] * 0.125f};
    if (writeMode) {
      ((f4*)op)[0] = v0;
      ((f4*)op)[1] = v1;
    } else {
      ((f4*)op)[0] += v0;
      ((f4*)op)[1] += v1;
    }
  }
}

// ---- host ----
extern "C" void kernel_launch(void* const* d_in, const int* in_sizes, int n_in,
                              void* d_out, int out_size, void* d_ws, size_t ws_size,
                              hipStream_t stream) {
  const float* x = (const float*)d_in[0];
  const int* srcp = (const int*)d_in[1];
  const int* dstp = (const int*)d_in[2];
  const float* Wl[3]  = {(const float*)d_in[3], (const float*)d_in[6], (const float*)d_in[9]};
  const float* alp[3] = {(const float*)d_in[4], (const float*)d_in[7], (const float*)d_in[10]};
  const float* arl[3] = {(const float*)d_in[5], (const float*)d_in[8], (const float*)d_in[11]};
  float* out = (float*)d_out;
  (void)in_sizes; (void)n_in; (void)out_size;

  auto rup = [](size_t b) { return (b + 255) & ~(size_t)255; };
  size_t need = 3 * rup((size_t)NNODES * FDIM * 2) +        // b0, b1, fbuf
                2 * rup((size_t)NNODES * NH * 2) +          // el, er (bf16)
                rup((size_t)NREL * FDIM * FDIM * 2) +       // Wt (all 4 relations)
                2 * rup((size_t)NREL * NNODES * 4) +        // deg, ptrf
                rup((size_t)NREL * NEDGE * 4);              // csrc
  if (ws_size < need) return;  // diagnostic: zeros out, no crash

  char* ws = (char*)d_ws;
  size_t off = 0;
  auto alloc = [&](size_t bytes) -> void* { void* p = ws + off; off += rup(bytes); return p; };
  __bf16* b0   = (__bf16*)alloc((size_t)NNODES * FDIM * 2);
  __bf16* b1   = (__bf16*)alloc((size_t)NNODES * FDIM * 2);
  __bf16* fbuf = (__bf16*)alloc((size_t)NNODES * FDIM * 2);
  __bf16* el   = (__bf16*)alloc((size_t)NNODES * NH * 2);
  __bf16* er   = (__bf16*)alloc((size_t)NNODES * NH * 2);
  __bf16* Wt   = (__bf16*)alloc((size_t)NREL * FDIM * FDIM * 2);
  int* deg  = (int*)alloc((size_t)NREL * NNODES * 4);
  int* ptrf = (int*)alloc((size_t)NREL * NNODES * 4);
  int* csrc = (int*)alloc((size_t)NREL * NEDGE * 4);
  // cur + bsum alias into fbuf (dead during CSR build)
  int* cur  = (int*)fbuf;
  int* bsum = (int*)((char*)fbuf + rup((size_t)NREL * NNODES * 4));

  // ---- CSR by dst ----
  hipMemsetAsync(deg, 0, (size_t)NREL * NNODES * 4, stream);
  hipMemsetAsync(cur, 0, (size_t)NREL * NNODES * 4, stream);
  k_count<<<dim3((NEDGE + 255) / 256, NREL), 256, 0, stream>>>(dstp, deg);
  int ntot = NREL * NNODES;
  int nb1 = (ntot + 1023) / 1024;
  k_scan_a<<<nb1, 256, 0, stream>>>(deg, ptrf, bsum, ntot);
  k_scan_b<<<1, 256, 0, stream>>>(bsum, nb1);
  k_scan_c<<<(ntot + 255) / 256, 256, 0, stream>>>(ptrf, bsum, ntot);
  k_scatter<<<dim3((NEDGE + 255) / 256, NREL), 256, 0, stream>>>(srcp, dstp, ptrf, cur, csrc);

  // layer-0 input: conv x -> b1 as [N,256] bf16
  k_conv<<<(NNODES * 256) / 1024, 256, 0, stream>>>(x, b1);

  int ngrid = NMB * 4;  // 3128 (128x128 tiles over [100000, 512])
  for (int L = 0; L < 3; L++) {
    int K = (L == 0) ? 256 : FDIM;
    const __bf16* inb = (L == 1) ? b0 : b1;  // L0:b1(x), L1:b0, L2:b1
    __bf16* outb = (L == 0) ? b0 : b1;       // L2 writes d_out instead
    k_transW<<<dim3(K / 32, 16, NREL), dim3(32, 8), 0, stream>>>(Wl[L], Wt, K);
    for (int r = 0; r < NREL; r++) {
      k_gemm<<<ngrid, 256, 0, stream>>>(inb, Wt + (size_t)r * FDIM * K, fbuf,
                                        alp[L] + (size_t)r * 512,
                                        arl[L] + (size_t)r * 512,
                                        el, er, NNODES, K);
      if (L < 2)
        k_agg<<<NNODES / 4, 256, 0, stream>>>(fbuf, el, er, ptrf + (size_t)r * NNODES,
                                              deg + (size_t)r * NNODES, csrc, outb,
                                              r == 0 ? 1 : 0);
      else
        k_aggm<<<NNODES / 4, 256, 0, stream>>>(fbuf, el, er, ptrf + (size_t)r * NNODES,
                                               deg + (size_t)r * NNODES, csrc, out,
                                               r == 0 ? 1 : 0);
    }
  }
}

// Round 13
// 1923.924 us; speedup vs baseline: 1.5190x; 1.5190x over previous
//
#include <hip/hip_runtime.h>
#include <hip/hip_bf16.h>
#include <math.h>

#define NNODES 100000
#define NREL 4
#define NEDGE 200000
#define NH 8
#define FDIM 512
#define NMB 782  // ceil(100000/128)

typedef float f4 __attribute__((ext_vector_type(4)));
typedef __bf16 bf16x8 __attribute__((ext_vector_type(8)));
typedef __bf16 bf16x4 __attribute__((ext_vector_type(4)));

__device__ __forceinline__ float eluf(float v) { return v > 0.f ? v : expm1f(v); }
__device__ __forceinline__ void gload16(const __bf16* g, __bf16* l) {
  __builtin_amdgcn_global_load_lds((const __attribute__((address_space(1))) void*)g,
                                   (__attribute__((address_space(3))) void*)l, 16, 0, 0);
}

// ---- f32 -> bf16 convert (count multiple of 1024) ----
__global__ void k_conv(const float* __restrict__ in, __bf16* __restrict__ outp) {
  int i = (blockIdx.x * 256 + threadIdx.x) * 4;
  f4 v = *(const f4*)(in + i);
  bf16x4 o = {(__bf16)v.x, (__bf16)v.y, (__bf16)v.z, (__bf16)v.w};
  *(bf16x4*)(outp + i) = o;
}

// ---- W [4,K,512] f32 -> Wt [4*512, K] bf16 (transposed), all relations ----
__global__ void k_transW(const float* __restrict__ W, __bf16* __restrict__ Wt, int K) {
  __shared__ float tile[32][33];
  int r = blockIdx.z;
  const float* Wr = W + (size_t)r * K * FDIM;
  __bf16* Wtr = Wt + (size_t)r * FDIM * K;
  int k0 = blockIdx.x * 32, n0 = blockIdx.y * 32;
  int tx = threadIdx.x, ty = threadIdx.y;
  for (int i = ty; i < 32; i += 8)
    tile[i][tx] = Wr[(size_t)(k0 + i) * FDIM + n0 + tx];
  __syncthreads();
  for (int i = ty; i < 32; i += 8)
    Wtr[(size_t)(n0 + i) * K + k0 + tx] = (__bf16)tile[tx][i];
}

// ---- bf16 MFMA GEMM (R11-proven): 128x256 tile, 2-buffer counted-vmcnt, bijective
//      XCD swizzle, fused el/er epilogue (bf16). C[M,512] = A[M,K]*BT[512,K]^T ----
__global__ __launch_bounds__(256, 2) void k_gemm(const __bf16* __restrict__ A,
                                                 const __bf16* __restrict__ BT,
                                                 __bf16* __restrict__ C,
                                                 const float* __restrict__ al,
                                                 const float* __restrict__ ar,
                                                 __bf16* __restrict__ el,
                                                 __bf16* __restrict__ er, int M, int K) {
  __shared__ alignas(16) __bf16 lA[2][128 * 32];
  __shared__ alignas(16) __bf16 lB[2][256 * 32];
  int t = threadIdx.x, l = t & 63, w = t >> 6;
  // bijective XCD-chunked swizzle (m204)
  int nwg = gridDim.x, q8 = nwg >> 3, r8 = nwg & 7;
  int xx = blockIdx.x & 7, loc = blockIdx.x >> 3;
  int swz = (xx < r8 ? xx * (q8 + 1) : r8 * (q8 + 1) + (xx - r8) * q8) + loc;
  int m0 = (swz >> 1) * 128, n0 = (swz & 1) * 256;
  int wm = (w >> 1) * 64, wn = (w & 1) * 128;
  f4 acc[4][8] = {};

  const __bf16* pA[2];
  const __bf16* pB[4];
#pragma unroll
  for (int u = 0; u < 2; u++) {
    int s = t + u * 256;
    int row = m0 + (s >> 2); if (row >= M) row = M - 1;
    pA[u] = A + (size_t)row * K + (((s & 3) ^ ((s >> 2) & 3)) * 8);
  }
#pragma unroll
  for (int u = 0; u < 4; u++) {
    int s = t + u * 256;
    pB[u] = BT + (size_t)(n0 + (s >> 2)) * K + (((s & 3) ^ ((s >> 2) & 3)) * 8);
  }

#define STAGE(buf, kk)                                      \
  do {                                                      \
    gload16(pA[0] + (kk), &lA[buf][t * 8]);                 \
    gload16(pA[1] + (kk), &lA[buf][(t + 256) * 8]);         \
    gload16(pB[0] + (kk), &lB[buf][t * 8]);                 \
    gload16(pB[1] + (kk), &lB[buf][(t + 256) * 8]);         \
    gload16(pB[2] + (kk), &lB[buf][(t + 512) * 8]);         \
    gload16(pB[3] + (kk), &lB[buf][(t + 768) * 8]);         \
  } while (0)

  int nt = K >> 5;
  STAGE(0, 0);
  STAGE(1, 32);
  int segoff = ((l >> 4) ^ (l & 3)) * 8;
  int rofA = (wm + (l & 15)) * 32 + segoff;
  int rofB = (wn + (l & 15)) * 32 + segoff;
  for (int kt = 0; kt < nt; kt++) {
    int cur = kt & 1;
    if (kt + 1 < nt) asm volatile("s_waitcnt vmcnt(6)" ::: "memory");
    else             asm volatile("s_waitcnt vmcnt(0)" ::: "memory");
    __builtin_amdgcn_s_barrier();
    bf16x8 a[4], b[8];
#pragma unroll
    for (int i = 0; i < 4; i++) a[i] = *(const bf16x8*)(&lA[cur][rofA + i * 512]);
#pragma unroll
    for (int j = 0; j < 8; j++) b[j] = *(const bf16x8*)(&lB[cur][rofB + j * 512]);
    asm volatile("s_waitcnt lgkmcnt(0)" ::: "memory");
    __builtin_amdgcn_s_barrier();
    if (kt + 2 < nt) STAGE(cur, (kt + 2) * 32);
#pragma unroll
    for (int i = 0; i < 4; i++)
#pragma unroll
      for (int j = 0; j < 8; j++)
        acc[i][j] = __builtin_amdgcn_mfma_f32_16x16x32_bf16(a[i], b[j], acc[i][j], 0, 0, 0);
  }
#undef STAGE

  // ---- C write (bf16, scalar stores — proven pattern) ----
  int cn = n0 + wn + (l & 15);
  int rbase = m0 + wm + (l >> 4) * 4;
#pragma unroll
  for (int i = 0; i < 4; i++)
#pragma unroll
    for (int q2 = 0; q2 < 4; q2++) {
      int row = rbase + i * 16 + q2;
      if (row < M) {
#pragma unroll
        for (int j = 0; j < 8; j++)
          C[(size_t)row * FDIM + cn + j * 16] = (__bf16)acc[i][j][q2];
      }
    }

  // ---- fused el/er (bf16 out): wave covers 2 heads (128 cols) ----
  int hbase = (n0 + wn) >> 6;
  float av[8], bv[8];
#pragma unroll
  for (int j = 0; j < 8; j++) {
    int h = hbase + (j >> 2);
    av[j] = al[h * 64 + (j & 3) * 16 + (l & 15)];
    bv[j] = ar[h * 64 + (j & 3) * 16 + (l & 15)];
  }
#pragma unroll
  for (int i = 0; i < 4; i++)
#pragma unroll
    for (int q2 = 0; q2 < 4; q2++) {
#pragma unroll
      for (int half = 0; half < 2; half++) {
        float se = acc[i][half * 4 + 0][q2] * av[half * 4 + 0] +
                   acc[i][half * 4 + 1][q2] * av[half * 4 + 1] +
                   acc[i][half * 4 + 2][q2] * av[half * 4 + 2] +
                   acc[i][half * 4 + 3][q2] * av[half * 4 + 3];
        float sr = acc[i][half * 4 + 0][q2] * bv[half * 4 + 0] +
                   acc[i][half * 4 + 1][q2] * bv[half * 4 + 1] +
                   acc[i][half * 4 + 2][q2] * bv[half * 4 + 2] +
                   acc[i][half * 4 + 3][q2] * bv[half * 4 + 3];
        se += __shfl_xor(se, 1); se += __shfl_xor(se, 2);
        se += __shfl_xor(se, 4); se += __shfl_xor(se, 8);
        sr += __shfl_xor(sr, 1); sr += __shfl_xor(sr, 2);
        sr += __shfl_xor(sr, 4); sr += __shfl_xor(sr, 8);
        if ((l & 15) == 0) {
          int row = rbase + i * 16 + q2;
          if (row < M) {
            int h = hbase + half;
            el[row * NH + h] = (__bf16)se;
            er[row * NH + h] = (__bf16)sr;
          }
        }
      }
    }
}

// ---- CSR build ----
__global__ void k_count(const int* __restrict__ dst, int* __restrict__ deg) {
  int e = blockIdx.x * 256 + threadIdx.x;
  int r = blockIdx.y;
  if (e < NEDGE) {
    int d = dst[(size_t)r * NEDGE + e];
    if ((unsigned)d < (unsigned)NNODES) atomicAdd(&deg[r * NNODES + d], 1);
  }
}

__global__ __launch_bounds__(256) void k_scan_a(const int* __restrict__ in, int* __restrict__ out,
                                                int* __restrict__ bsum, int n) {
  __shared__ int wsums[4];
  int t = threadIdx.x, lane = t & 63, w = t >> 6;
  int base = blockIdx.x * 1024 + t * 4;
  int v0 = base + 0 < n ? in[base + 0] : 0;
  int v1 = base + 1 < n ? in[base + 1] : 0;
  int v2 = base + 2 < n ? in[base + 2] : 0;
  int v3 = base + 3 < n ? in[base + 3] : 0;
  int tot = v0 + v1 + v2 + v3;
  int sc = tot;
#pragma unroll
  for (int off = 1; off < 64; off <<= 1) {
    int u = __shfl_up(sc, off);
    if (lane >= off) sc += u;
  }
  if (lane == 63) wsums[w] = sc;
  __syncthreads();
  int add = 0;
#pragma unroll
  for (int i = 0; i < 4; i++)
    if (i < w) add += wsums[i];
  int excl = add + sc - tot;
  if (base + 0 < n) out[base + 0] = excl;
  if (base + 1 < n) out[base + 1] = excl + v0;
  if (base + 2 < n) out[base + 2] = excl + v0 + v1;
  if (base + 3 < n) out[base + 3] = excl + v0 + v1 + v2;
  if (t == 255) bsum[blockIdx.x] = add + sc;
}

__global__ __launch_bounds__(256) void k_scan_b(int* __restrict__ bsum, int nb) {
  __shared__ int wsums[4];
  int t = threadIdx.x, lane = t & 63, w = t >> 6;
  int i0 = t * 2, i1 = t * 2 + 1;
  int v0 = i0 < nb ? bsum[i0] : 0;
  int v1 = i1 < nb ? bsum[i1] : 0;
  int tot = v0 + v1, sc = tot;
#pragma unroll
  for (int off = 1; off < 64; off <<= 1) {
    int u = __shfl_up(sc, off);
    if (lane >= off) sc += u;
  }
  if (lane == 63) wsums[w] = sc;
  __syncthreads();
  int add = 0;
#pragma unroll
  for (int i = 0; i < 4; i++)
    if (i < w) add += wsums[i];
  int excl = add + sc - tot;
  if (i0 < nb) bsum[i0] = excl;
  if (i1 < nb) bsum[i1] = excl + v0;
}

__global__ void k_scan_c(int* __restrict__ out, const int* __restrict__ bsum, int n) {
  int i = blockIdx.x * 256 + threadIdx.x;
  if (i < n) out[i] += bsum[i >> 10];
}

__global__ void k_scatter(const int* __restrict__ src, const int* __restrict__ dst,
                          const int* __restrict__ ptrf, int* __restrict__ cur,
                          int* __restrict__ csrc) {
  int e = blockIdx.x * 256 + threadIdx.x;
  int r = blockIdx.y;
  if (e >= NEDGE) return;
  int d = dst[(size_t)r * NEDGE + e];
  if ((unsigned)d >= (unsigned)NNODES) return;
  int slot = ptrf[r * NNODES + d] + atomicAdd(&cur[r * NNODES + d], 1);
  if ((unsigned)slot < (unsigned)(NREL * NEDGE))
    csrc[slot] = src[(size_t)r * NEDGE + e];
}

// ---- fused segment-softmax + aggregate + ELU, edge-unroll-2 dual accumulators;
//      writeMode=1: full write (replaces memset) ----
__global__ void k_agg(const __bf16* __restrict__ f, const __bf16* __restrict__ el,
                      const __bf16* __restrict__ er, const int* __restrict__ ptrf,
                      const int* __restrict__ deg, const int* __restrict__ csrc,
                      __bf16* __restrict__ accG, int writeMode) {
  int t = threadIdx.x;
  int l = t & 63;
  int d = blockIdx.x * 4 + (t >> 6);
  int h = l >> 3;
  int cnt = deg[d];
  float res[8] = {0.f, 0.f, 0.f, 0.f, 0.f, 0.f, 0.f, 0.f};
  if (cnt > 0) {
    int start = ptrf[d];
    if (start < 0) start = 0;
    if (start > NREL * NEDGE) start = NREL * NEDGE;
    if (cnt > NREL * NEDGE - start) cnt = NREL * NEDGE - start;
    float erh = (float)er[d * NH + h];
    float a0[8] = {0.f, 0.f, 0.f, 0.f, 0.f, 0.f, 0.f, 0.f};
    float a1[8] = {0.f, 0.f, 0.f, 0.f, 0.f, 0.f, 0.f, 0.f};
    float den = 0.f;
    int j = 0;
    for (; j + 1 < cnt; j += 2) {  // dual-issue: both gathers in flight together
      int s0 = csrc[start + j], s1 = csrc[start + j + 1];
      if ((unsigned)s0 >= (unsigned)NNODES) s0 = 0;
      if ((unsigned)s1 >= (unsigned)NNODES) s1 = 0;
      bf16x8 fv0 = *(const bf16x8*)(f + (size_t)s0 * FDIM + l * 8);
      bf16x8 fv1 = *(const bf16x8*)(f + (size_t)s1 * FDIM + l * 8);
      float e0 = (float)el[s0 * NH + h] + erh;
      float e1 = (float)el[s1 * NH + h] + erh;
      e0 = (e0 > 0.f) ? e0 : 0.2f * e0;
      e1 = (e1 > 0.f) ? e1 : 0.2f * e1;
      float ex0 = __expf(e0), ex1 = __expf(e1);
      den += ex0 + ex1;
#pragma unroll
      for (int i = 0; i < 8; i++) {
        a0[i] += ex0 * (float)fv0[i];
        a1[i] += ex1 * (float)fv1[i];
      }
    }
    if (j < cnt) {
      int s0 = csrc[start + j];
      if ((unsigned)s0 >= (unsigned)NNODES) s0 = 0;
      bf16x8 fv0 = *(const bf16x8*)(f + (size_t)s0 * FDIM + l * 8);
      float e0 = (float)el[s0 * NH + h] + erh;
      e0 = (e0 > 0.f) ? e0 : 0.2f * e0;
      float ex0 = __expf(e0);
      den += ex0;
#pragma unroll
      for (int i = 0; i < 8; i++) a0[i] += ex0 * (float)fv0[i];
    }
    float inv = 1.f / (den + 1e-9f);
#pragma unroll
    for (int i = 0; i < 8; i++) res[i] = eluf((a0[i] + a1[i]) * inv);
  } else if (!writeMode) {
    return;
  }
  __bf16* ap = accG + (size_t)d * FDIM + l * 8;
  bf16x8 o;
  if (writeMode) {
#pragma unroll
    for (int i = 0; i < 8; i++) o[i] = (__bf16)res[i];
  } else {
    bf16x8 cv = *(bf16x8*)ap;
#pragma unroll
    for (int i = 0; i < 8; i++) o[i] = (__bf16)((float)cv[i] + res[i]);
  }
  *(bf16x8*)ap = o;
}

// ---- layer-2 agg with FUSED head-mean (writes out[N,64] f32), edge-unroll-2 ----
__global__ void k_aggm(const __bf16* __restrict__ f, const __bf16* __restrict__ el,
                       const __bf16* __restrict__ er, const int* __restrict__ ptrf,
                       const int* __restrict__ deg, const int* __restrict__ csrc,
                       float* __restrict__ out, int writeMode) {
  int t = threadIdx.x;
  int l = t & 63;
  int d = blockIdx.x * 4 + (t >> 6);
  int h = l >> 3;
  int cnt = deg[d];
  float res[8] = {0.f, 0.f, 0.f, 0.f, 0.f, 0.f, 0.f, 0.f};
  if (cnt > 0) {
    int start = ptrf[d];
    if (start < 0) start = 0;
    if (start > NREL * NEDGE) start = NREL * NEDGE;
    if (cnt > NREL * NEDGE - start) cnt = NREL * NEDGE - start;
    float erh = (float)er[d * NH + h];
    float a0[8] = {0.f, 0.f, 0.f, 0.f, 0.f, 0.f, 0.f, 0.f};
    float a1[8] = {0.f, 0.f, 0.f, 0.f, 0.f, 0.f, 0.f, 0.f};
    float den = 0.f;
    int j = 0;
    for (; j + 1 < cnt; j += 2) {
      int s0 = csrc[start + j], s1 = csrc[start + j + 1];
      if ((unsigned)s0 >= (unsigned)NNODES) s0 = 0;
      if ((unsigned)s1 >= (unsigned)NNODES) s1 = 0;
      bf16x8 fv0 = *(const bf16x8*)(f + (size_t)s0 * FDIM + l * 8);
      bf16x8 fv1 = *(const bf16x8*)(f + (size_t)s1 * FDIM + l * 8);
      float e0 = (float)el[s0 * NH + h] + erh;
      float e1 = (float)el[s1 * NH + h] + erh;
      e0 = (e0 > 0.f) ? e0 : 0.2f * e0;
      e1 = (e1 > 0.f) ? e1 : 0.2f * e1;
      float ex0 = __expf(e0), ex1 = __expf(e1);
      den += ex0 + ex1;
#pragma unroll
      for (int i = 0; i < 8; i++) {
        a0[i] += ex0 * (float)fv0[i];
        a1[i] += ex1 * (float)fv1[i];
      }
    }
    if (j < cnt) {
      int s0 = csrc[start + j];
      if ((unsigned)s0 >= (unsigned)NNODES) s0 = 0;
      bf16x8 fv0 = *(const bf16x8*)(f + (size_t)s0 * FDIM + l * 8);
      float e0 = (float)el[s0 * NH + h] + erh;
      e0 = (e0 > 0.f) ? e0 : 0.2f * e0;
      float ex0 = __expf(e0);
      den += ex0;
#pragma unroll
      for (int i = 0; i < 8; i++) a0[i] += ex0 * (float)fv0[i];
    }
    float inv = 1.f / (den + 1e-9f);
#pragma unroll
    for (int i = 0; i < 8; i++) res[i] = eluf((a0[i] + a1[i]) * inv);
  }
  // cross-head sum: lanes with same (l&7) across the 8 head-groups
#pragma unroll
  for (int i = 0; i < 8; i++) {
    res[i] += __shfl_xor(res[i], 8);
    res[i] += __shfl_xor(res[i], 16);
    res[i] += __shfl_xor(res[i], 32);
  }
  if (l < 8) {
    float* op = out + (size_t)d * 64 + l * 8;
    f4 v0 = {res[0] * 0.125f, res[1] * 0.125f, res[2] * 0.125f, res[3] * 0.125f};
    f4 v1 = {res[4] * 0.125f, res[5] * 0.125f, res[6] * 0.125f, res[7] * 0.125f};
    if (writeMode) {
      ((f4*)op)[0] = v0;
      ((f4*)op)[1] = v1;
    } else {
      ((f4*)op)[0] += v0;
      ((f4*)op)[1] += v1;
    }
  }
}

// ---- host ----
extern "C" void kernel_launch(void* const* d_in, const int* in_sizes, int n_in,
                              void* d_out, int out_size, void* d_ws, size_t ws_size,
                              hipStream_t stream) {
  const float* x = (const float*)d_in[0];
  const int* srcp = (const int*)d_in[1];
  const int* dstp = (const int*)d_in[2];
  const float* Wl[3]  = {(const float*)d_in[3], (const float*)d_in[6], (const float*)d_in[9]};
  const float* alp[3] = {(const float*)d_in[4], (const float*)d_in[7], (const float*)d_in[10]};
  const float* arl[3] = {(const float*)d_in[5], (const float*)d_in[8], (const float*)d_in[11]};
  float* out = (float*)d_out;
  (void)in_sizes; (void)n_in; (void)out_size;

  auto rup = [](size_t b) { return (b + 255) & ~(size_t)255; };
  size_t need = 3 * rup((size_t)NNODES * FDIM * 2) +        // b0, b1, fbuf
                2 * rup((size_t)NNODES * NH * 2) +          // el, er (bf16)
                rup((size_t)NREL * FDIM * FDIM * 2) +       // Wt (all 4 relations)
                2 * rup((size_t)NREL * NNODES * 4) +        // deg, ptrf
                rup((size_t)NREL * NEDGE * 4);              // csrc
  if (ws_size < need) return;  // diagnostic: zeros out, no crash

  char* ws = (char*)d_ws;
  size_t off = 0;
  auto alloc = [&](size_t bytes) -> void* { void* p = ws + off; off += rup(bytes); return p; };
  __bf16* b0   = (__bf16*)alloc((size_t)NNODES * FDIM * 2);
  __bf16* b1   = (__bf16*)alloc((size_t)NNODES * FDIM * 2);
  __bf16* fbuf = (__bf16*)alloc((size_t)NNODES * FDIM * 2);
  __bf16* el   = (__bf16*)alloc((size_t)NNODES * NH * 2);
  __bf16* er   = (__bf16*)alloc((size_t)NNODES * NH * 2);
  __bf16* Wt   = (__bf16*)alloc((size_t)NREL * FDIM * FDIM * 2);
  int* deg  = (int*)alloc((size_t)NREL * NNODES * 4);
  int* ptrf = (int*)alloc((size_t)NREL * NNODES * 4);
  int* csrc = (int*)alloc((size_t)NREL * NEDGE * 4);
  // cur + bsum alias into fbuf (dead during CSR build)
  int* cur  = (int*)fbuf;
  int* bsum = (int*)((char*)fbuf + rup((size_t)NREL * NNODES * 4));

  // ---- CSR by dst ----
  hipMemsetAsync(deg, 0, (size_t)NREL * NNODES * 4, stream);
  hipMemsetAsync(cur, 0, (size_t)NREL * NNODES * 4, stream);
  k_count<<<dim3((NEDGE + 255) / 256, NREL), 256, 0, stream>>>(dstp, deg);
  int ntot = NREL * NNODES;
  int nb1 = (ntot + 1023) / 1024;
  k_scan_a<<<nb1, 256, 0, stream>>>(deg, ptrf, bsum, ntot);
  k_scan_b<<<1, 256, 0, stream>>>(bsum, nb1);
  k_scan_c<<<(ntot + 255) / 256, 256, 0, stream>>>(ptrf, bsum, ntot);
  k_scatter<<<dim3((NEDGE + 255) / 256, NREL), 256, 0, stream>>>(srcp, dstp, ptrf, cur, csrc);

  // layer-0 input: conv x -> b1 as [N,256] bf16
  k_conv<<<(NNODES * 256) / 1024, 256, 0, stream>>>(x, b1);

  int ngrid = NMB * 2;  // 1564 (128x256 tiles over [100000, 512])
  for (int L = 0; L < 3; L++) {
    int K = (L == 0) ? 256 : FDIM;
    const __bf16* inb = (L == 1) ? b0 : b1;  // L0:b1(x), L1:b0, L2:b1
    __bf16* outb = (L == 0) ? b0 : b1;       // L2 writes d_out instead
    k_transW<<<dim3(K / 32, 16, NREL), dim3(32, 8), 0, stream>>>(Wl[L], Wt, K);
    for (int r = 0; r < NREL; r++) {
      k_gemm<<<ngrid, 256, 0, stream>>>(inb, Wt + (size_t)r * FDIM * K, fbuf,
                                        alp[L] + (size_t)r * 512,
                                        arl[L] + (size_t)r * 512,
                                        el, er, NNODES, K);
      if (L < 2)
        k_agg<<<NNODES / 4, 256, 0, stream>>>(fbuf, el, er, ptrf + (size_t)r * NNODES,
                                              deg + (size_t)r * NNODES, csrc, outb,
                                              r == 0 ? 1 : 0);
      else
        k_aggm<<<NNODES / 4, 256, 0, stream>>>(fbuf, el, er, ptrf + (size_t)r * NNODES,
                                               deg + (size_t)r * NNODES, csrc, out,
                                               r == 0 ? 1 : 0);
    }
  }
}

// Round 14
// 1868.199 us; speedup vs baseline: 1.5643x; 1.0298x over previous
//
#include <hip/hip_runtime.h>
#include <hip/hip_bf16.h>
#include <math.h>

#define NNODES 100000
#define NREL 4
#define NEDGE 200000
#define NH 8
#define FDIM 512
#define NMB 782  // ceil(100000/128)

typedef float f4 __attribute__((ext_vector_type(4)));
typedef __bf16 bf16x8 __attribute__((ext_vector_type(8)));
typedef __bf16 bf16x4 __attribute__((ext_vector_type(4)));

__device__ __forceinline__ float eluf(float v) { return v > 0.f ? v : expm1f(v); }
__device__ __forceinline__ void gload16(const __bf16* g, __bf16* l) {
  __builtin_amdgcn_global_load_lds((const __attribute__((address_space(1))) void*)g,
                                   (__attribute__((address_space(3))) void*)l, 16, 0, 0);
}

// ---- f32 -> bf16 convert (count multiple of 1024) ----
__global__ void k_conv(const float* __restrict__ in, __bf16* __restrict__ outp) {
  int i = (blockIdx.x * 256 + threadIdx.x) * 4;
  f4 v = *(const f4*)(in + i);
  bf16x4 o = {(__bf16)v.x, (__bf16)v.y, (__bf16)v.z, (__bf16)v.w};
  *(bf16x4*)(outp + i) = o;
}

// ---- W [4,K,512] f32 -> Wt [4*512, K] bf16 (transposed), all relations ----
__global__ void k_transW(const float* __restrict__ W, __bf16* __restrict__ Wt, int K) {
  __shared__ float tile[32][33];
  int r = blockIdx.z;
  const float* Wr = W + (size_t)r * K * FDIM;
  __bf16* Wtr = Wt + (size_t)r * FDIM * K;
  int k0 = blockIdx.x * 32, n0 = blockIdx.y * 32;
  int tx = threadIdx.x, ty = threadIdx.y;
  for (int i = ty; i < 32; i += 8)
    tile[i][tx] = Wr[(size_t)(k0 + i) * FDIM + n0 + tx];
  __syncthreads();
  for (int i = ty; i < 32; i += 8)
    Wtr[(size_t)(n0 + i) * K + k0 + tx] = (__bf16)tile[tx][i];
}

// ---- bf16 MFMA GEMM: BK=64, ONE barrier per K-tile (4x fewer rendezvous),
//      128x128 tile, 2x32KB buffers (2 blocks/CU), XOR-swizzled LDS,
//      bijective XCD swizzle, fused el/er epilogue. C[M,512]=A[M,K]*BT^T ----
__global__ __launch_bounds__(256) void k_gemm(const __bf16* __restrict__ A,
                                              const __bf16* __restrict__ BT,
                                              __bf16* __restrict__ C,
                                              const float* __restrict__ al,
                                              const float* __restrict__ ar,
                                              __bf16* __restrict__ el,
                                              __bf16* __restrict__ er, int M, int K) {
  __shared__ alignas(16) __bf16 lds[2][2][128 * 64];  // [buf][A|B][128 rows][64 cols]
  int t = threadIdx.x, l = t & 63, w = t >> 6;
  // bijective XCD-chunked swizzle (m204)
  int nwg = gridDim.x, q8 = nwg >> 3, r8 = nwg & 7;
  int xx = blockIdx.x & 7, loc = blockIdx.x >> 3;
  int swz = (xx < r8 ? xx * (q8 + 1) : r8 * (q8 + 1) + (xx - r8) * q8) + loc;
  int m0 = (swz >> 2) * 128, n0 = (swz & 3) * 128;
  int wm = (w >> 1) * 64, wn = (w & 1) * 64;
  f4 acc[4][4] = {};

  // staging sources: thread t, chunk u -> s=t+u*256; row=s>>3, chunk c=s&7;
  // source col pre-swizzled (c ^ (row&7)) so LDS-linear dest + swizzled read match
  const __bf16* pSA[4];
  const __bf16* pSB[4];
#pragma unroll
  for (int u = 0; u < 4; u++) {
    int s = t + u * 256;
    int row = s >> 3, c = s & 7;
    int scol = ((c ^ (row & 7)) * 8);
    int ra = m0 + row; if (ra >= M) ra = M - 1;
    pSA[u] = A + (size_t)ra * K + scol;
    pSB[u] = BT + (size_t)(n0 + row) * K + scol;
  }

#define STG(buf, kk)                                          \
  do {                                                        \
    gload16(pSA[0] + (kk), &lds[buf][0][(t) * 8]);            \
    gload16(pSA[1] + (kk), &lds[buf][0][(t + 256) * 8]);      \
    gload16(pSA[2] + (kk), &lds[buf][0][(t + 512) * 8]);      \
    gload16(pSA[3] + (kk), &lds[buf][0][(t + 768) * 8]);      \
    gload16(pSB[0] + (kk), &lds[buf][1][(t) * 8]);            \
    gload16(pSB[1] + (kk), &lds[buf][1][(t + 256) * 8]);      \
    gload16(pSB[2] + (kk), &lds[buf][1][(t + 512) * 8]);      \
    gload16(pSB[3] + (kk), &lds[buf][1][(t + 768) * 8]);      \
  } while (0)

  // swizzled read offsets (elems): row*64 + (chunk ^ (row&7))*8, chunk = ks*4 + (l>>4)
  int rA[4], rB[4];
#pragma unroll
  for (int i = 0; i < 4; i++) {
    int rowA = wm + i * 16 + (l & 15);
    int rowB = wn + i * 16 + (l & 15);
    rA[i] = rowA * 64;
    rB[i] = rowB * 64;
  }
  int ch0 = (l >> 4);  // base chunk within K-slice

  int nt = K >> 6;  // 8 (K=512) or 4 (K=256)
  STG(0, 0);
  for (int kt = 0; kt < nt; kt++) {
    int cb = kt & 1;
    asm volatile("s_waitcnt vmcnt(0)" ::: "memory");  // own tile-kt loads landed (issued a full tile ago)
    __builtin_amdgcn_s_barrier();                     // all waves landed kt; buf (kt+1)&1 free
    __builtin_amdgcn_sched_barrier(0);
    if (kt + 1 < nt) STG(cb ^ 1, (kt + 1) * 64);      // prefetch flies under this tile's compute
    bf16x8 a[4][2], b[4][2];
#pragma unroll
    for (int ks = 0; ks < 2; ks++)
#pragma unroll
      for (int i = 0; i < 4; i++) {
        int ch = ks * 4 + ch0;
        int rowA7 = (rA[i] >> 6) & 7;
        int rowB7 = (rB[i] >> 6) & 7;
        a[i][ks] = *(const bf16x8*)(&lds[cb][0][rA[i] + ((ch ^ rowA7) * 8)]);
        b[i][ks] = *(const bf16x8*)(&lds[cb][1][rB[i] + ((ch ^ rowB7) * 8)]);
      }
#pragma unroll
    for (int ks = 0; ks < 2; ks++)
#pragma unroll
      for (int i = 0; i < 4; i++)
#pragma unroll
        for (int j = 0; j < 4; j++)
          acc[i][j] = __builtin_amdgcn_mfma_f32_16x16x32_bf16(a[i][ks], b[j][ks], acc[i][j], 0, 0, 0);
  }
#undef STG

  // ---- C write (bf16, scalar stores — proven pattern) ----
  int cn = n0 + wn + (l & 15);
  int rbase = m0 + wm + (l >> 4) * 4;
#pragma unroll
  for (int i = 0; i < 4; i++)
#pragma unroll
    for (int q2 = 0; q2 < 4; q2++) {
      int row = rbase + i * 16 + q2;
      if (row < M) {
#pragma unroll
        for (int j = 0; j < 4; j++)
          C[(size_t)row * FDIM + cn + j * 16] = (__bf16)acc[i][j][q2];
      }
    }

  // ---- fused el/er (bf16 out): wave's 64-col slice == one head ----
  int h = (n0 + wn) >> 6;
  float av[4], bv[4];
#pragma unroll
  for (int j = 0; j < 4; j++) {
    av[j] = al[h * 64 + j * 16 + (l & 15)];
    bv[j] = ar[h * 64 + j * 16 + (l & 15)];
  }
#pragma unroll
  for (int i = 0; i < 4; i++)
#pragma unroll
    for (int q2 = 0; q2 < 4; q2++) {
      float se = acc[i][0][q2] * av[0] + acc[i][1][q2] * av[1] +
                 acc[i][2][q2] * av[2] + acc[i][3][q2] * av[3];
      float sr = acc[i][0][q2] * bv[0] + acc[i][1][q2] * bv[1] +
                 acc[i][2][q2] * bv[2] + acc[i][3][q2] * bv[3];
      se += __shfl_xor(se, 1); se += __shfl_xor(se, 2);
      se += __shfl_xor(se, 4); se += __shfl_xor(se, 8);
      sr += __shfl_xor(sr, 1); sr += __shfl_xor(sr, 2);
      sr += __shfl_xor(sr, 4); sr += __shfl_xor(sr, 8);
      if ((l & 15) == 0) {
        int row = rbase + i * 16 + q2;
        if (row < M) {
          el[row * NH + h] = (__bf16)se;
          er[row * NH + h] = (__bf16)sr;
        }
      }
    }
}

// ---- CSR build ----
__global__ void k_count(const int* __restrict__ dst, int* __restrict__ deg) {
  int e = blockIdx.x * 256 + threadIdx.x;
  int r = blockIdx.y;
  if (e < NEDGE) {
    int d = dst[(size_t)r * NEDGE + e];
    if ((unsigned)d < (unsigned)NNODES) atomicAdd(&deg[r * NNODES + d], 1);
  }
}

__global__ __launch_bounds__(256) void k_scan_a(const int* __restrict__ in, int* __restrict__ out,
                                                int* __restrict__ bsum, int n) {
  __shared__ int wsums[4];
  int t = threadIdx.x, lane = t & 63, w = t >> 6;
  int base = blockIdx.x * 1024 + t * 4;
  int v0 = base + 0 < n ? in[base + 0] : 0;
  int v1 = base + 1 < n ? in[base + 1] : 0;
  int v2 = base + 2 < n ? in[base + 2] : 0;
  int v3 = base + 3 < n ? in[base + 3] : 0;
  int tot = v0 + v1 + v2 + v3;
  int sc = tot;
#pragma unroll
  for (int off = 1; off < 64; off <<= 1) {
    int u = __shfl_up(sc, off);
    if (lane >= off) sc += u;
  }
  if (lane == 63) wsums[w] = sc;
  __syncthreads();
  int add = 0;
#pragma unroll
  for (int i = 0; i < 4; i++)
    if (i < w) add += wsums[i];
  int excl = add + sc - tot;
  if (base + 0 < n) out[base + 0] = excl;
  if (base + 1 < n) out[base + 1] = excl + v0;
  if (base + 2 < n) out[base + 2] = excl + v0 + v1;
  if (base + 3 < n) out[base + 3] = excl + v0 + v1 + v2;
  if (t == 255) bsum[blockIdx.x] = add + sc;
}

__global__ __launch_bounds__(256) void k_scan_b(int* __restrict__ bsum, int nb) {
  __shared__ int wsums[4];
  int t = threadIdx.x, lane = t & 63, w = t >> 6;
  int i0 = t * 2, i1 = t * 2 + 1;
  int v0 = i0 < nb ? bsum[i0] : 0;
  int v1 = i1 < nb ? bsum[i1] : 0;
  int tot = v0 + v1, sc = tot;
#pragma unroll
  for (int off = 1; off < 64; off <<= 1) {
    int u = __shfl_up(sc, off);
    if (lane >= off) sc += u;
  }
  if (lane == 63) wsums[w] = sc;
  __syncthreads();
  int add = 0;
#pragma unroll
  for (int i = 0; i < 4; i++)
    if (i < w) add += wsums[i];
  int excl = add + sc - tot;
  if (i0 < nb) bsum[i0] = excl;
  if (i1 < nb) bsum[i1] = excl + v0;
}

__global__ void k_scan_c(int* __restrict__ out, const int* __restrict__ bsum, int n) {
  int i = blockIdx.x * 256 + threadIdx.x;
  if (i < n) out[i] += bsum[i >> 10];
}

__global__ void k_scatter(const int* __restrict__ src, const int* __restrict__ dst,
                          const int* __restrict__ ptrf, int* __restrict__ cur,
                          int* __restrict__ csrc) {
  int e = blockIdx.x * 256 + threadIdx.x;
  int r = blockIdx.y;
  if (e >= NEDGE) return;
  int d = dst[(size_t)r * NEDGE + e];
  if ((unsigned)d >= (unsigned)NNODES) return;
  int slot = ptrf[r * NNODES + d] + atomicAdd(&cur[r * NNODES + d], 1);
  if ((unsigned)slot < (unsigned)(NREL * NEDGE))
    csrc[slot] = src[(size_t)r * NEDGE + e];
}

// ---- fused segment-softmax + aggregate + ELU, edge-unroll-2 dual accumulators;
//      writeMode=1: full write (replaces memset) ----
__global__ void k_agg(const __bf16* __restrict__ f, const __bf16* __restrict__ el,
                      const __bf16* __restrict__ er, const int* __restrict__ ptrf,
                      const int* __restrict__ deg, const int* __restrict__ csrc,
                      __bf16* __restrict__ accG, int writeMode) {
  int t = threadIdx.x;
  int l = t & 63;
  int d = blockIdx.x * 4 + (t >> 6);
  int h = l >> 3;
  int cnt = deg[d];
  float res[8] = {0.f, 0.f, 0.f, 0.f, 0.f, 0.f, 0.f, 0.f};
  if (cnt > 0) {
    int start = ptrf[d];
    if (start < 0) start = 0;
    if (start > NREL * NEDGE) start = NREL * NEDGE;
    if (cnt > NREL * NEDGE - start) cnt = NREL * NEDGE - start;
    float erh = (float)er[d * NH + h];
    float a0[8] = {0.f, 0.f, 0.f, 0.f, 0.f, 0.f, 0.f, 0.f};
    float a1[8] = {0.f, 0.f, 0.f, 0.f, 0.f, 0.f, 0.f, 0.f};
    float den = 0.f;
    int j = 0;
    for (; j + 1 < cnt; j += 2) {  // dual-issue: both gathers in flight together
      int s0 = csrc[start + j], s1 = csrc[start + j + 1];
      if ((unsigned)s0 >= (unsigned)NNODES) s0 = 0;
      if ((unsigned)s1 >= (unsigned)NNODES) s1 = 0;
      bf16x8 fv0 = *(const bf16x8*)(f + (size_t)s0 * FDIM + l * 8);
      bf16x8 fv1 = *(const bf16x8*)(f + (size_t)s1 * FDIM + l * 8);
      float e0 = (float)el[s0 * NH + h] + erh;
      float e1 = (float)el[s1 * NH + h] + erh;
      e0 = (e0 > 0.f) ? e0 : 0.2f * e0;
      e1 = (e1 > 0.f) ? e1 : 0.2f * e1;
      float ex0 = __expf(e0), ex1 = __expf(e1);
      den += ex0 + ex1;
#pragma unroll
      for (int i = 0; i < 8; i++) {
        a0[i] += ex0 * (float)fv0[i];
        a1[i] += ex1 * (float)fv1[i];
      }
    }
    if (j < cnt) {
      int s0 = csrc[start + j];
      if ((unsigned)s0 >= (unsigned)NNODES) s0 = 0;
      bf16x8 fv0 = *(const bf16x8*)(f + (size_t)s0 * FDIM + l * 8);
      float e0 = (float)el[s0 * NH + h] + erh;
      e0 = (e0 > 0.f) ? e0 : 0.2f * e0;
      float ex0 = __expf(e0);
      den += ex0;
#pragma unroll
      for (int i = 0; i < 8; i++) a0[i] += ex0 * (float)fv0[i];
    }
    float inv = 1.f / (den + 1e-9f);
#pragma unroll
    for (int i = 0; i < 8; i++) res[i] = eluf((a0[i] + a1[i]) * inv);
  } else if (!writeMode) {
    return;
  }
  __bf16* ap = accG + (size_t)d * FDIM + l * 8;
  bf16x8 o;
  if (writeMode) {
#pragma unroll
    for (int i = 0; i < 8; i++) o[i] = (__bf16)res[i];
  } else {
    bf16x8 cv = *(bf16x8*)ap;
#pragma unroll
    for (int i = 0; i < 8; i++) o[i] = (__bf16)((float)cv[i] + res[i]);
  }
  *(bf16x8*)ap = o;
}

// ---- layer-2 agg with FUSED head-mean (writes out[N,64] f32), edge-unroll-2 ----
__global__ void k_aggm(const __bf16* __restrict__ f, const __bf16* __restrict__ el,
                       const __bf16* __restrict__ er, const int* __restrict__ ptrf,
                       const int* __restrict__ deg, const int* __restrict__ csrc,
                       float* __restrict__ out, int writeMode) {
  int t = threadIdx.x;
  int l = t & 63;
  int d = blockIdx.x * 4 + (t >> 6);
  int h = l >> 3;
  int cnt = deg[d];
  float res[8] = {0.f, 0.f, 0.f, 0.f, 0.f, 0.f, 0.f, 0.f};
  if (cnt > 0) {
    int start = ptrf[d];
    if (start < 0) start = 0;
    if (start > NREL * NEDGE) start = NREL * NEDGE;
    if (cnt > NREL * NEDGE - start) cnt = NREL * NEDGE - start;
    float erh = (float)er[d * NH + h];
    float a0[8] = {0.f, 0.f, 0.f, 0.f, 0.f, 0.f, 0.f, 0.f};
    float a1[8] = {0.f, 0.f, 0.f, 0.f, 0.f, 0.f, 0.f, 0.f};
    float den = 0.f;
    int j = 0;
    for (; j + 1 < cnt; j += 2) {
      int s0 = csrc[start + j], s1 = csrc[start + j + 1];
      if ((unsigned)s0 >= (unsigned)NNODES) s0 = 0;
      if ((unsigned)s1 >= (unsigned)NNODES) s1 = 0;
      bf16x8 fv0 = *(const bf16x8*)(f + (size_t)s0 * FDIM + l * 8);
      bf16x8 fv1 = *(const bf16x8*)(f + (size_t)s1 * FDIM + l * 8);
      float e0 = (float)el[s0 * NH + h] + erh;
      float e1 = (float)el[s1 * NH + h] + erh;
      e0 = (e0 > 0.f) ? e0 : 0.2f * e0;
      e1 = (e1 > 0.f) ? e1 : 0.2f * e1;
      float ex0 = __expf(e0), ex1 = __expf(e1);
      den += ex0 + ex1;
#pragma unroll
      for (int i = 0; i < 8; i++) {
        a0[i] += ex0 * (float)fv0[i];
        a1[i] += ex1 * (float)fv1[i];
      }
    }
    if (j < cnt) {
      int s0 = csrc[start + j];
      if ((unsigned)s0 >= (unsigned)NNODES) s0 = 0;
      bf16x8 fv0 = *(const bf16x8*)(f + (size_t)s0 * FDIM + l * 8);
      float e0 = (float)el[s0 * NH + h] + erh;
      e0 = (e0 > 0.f) ? e0 : 0.2f * e0;
      float ex0 = __expf(e0);
      den += ex0;
#pragma unroll
      for (int i = 0; i < 8; i++) a0[i] += ex0 * (float)fv0[i];
    }
    float inv = 1.f / (den + 1e-9f);
#pragma unroll
    for (int i = 0; i < 8; i++) res[i] = eluf((a0[i] + a1[i]) * inv);
  }
  // cross-head sum: lanes with same (l&7) across the 8 head-groups
#pragma unroll
  for (int i = 0; i < 8; i++) {
    res[i] += __shfl_xor(res[i], 8);
    res[i] += __shfl_xor(res[i], 16);
    res[i] += __shfl_xor(res[i], 32);
  }
  if (l < 8) {
    float* op = out + (size_t)d * 64 + l * 8;
    f4 v0 = {res[0] * 0.125f, res[1] * 0.125f, res[2] * 0.125f, res[3] * 0.125f};
    f4 v1 = {res[4] * 0.125f, res[5] * 0.125f, res[6] * 0.125f, res[7] * 0.125f};
    if (writeMode) {
      ((f4*)op)[0] = v0;
      ((f4*)op)[1] = v1;
    } else {
      ((f4*)op)[0] += v0;
      ((f4*)op)[1] += v1;
    }
  }
}

// ---- host ----
extern "C" void kernel_launch(void* const* d_in, const int* in_sizes, int n_in,
                              void* d_out, int out_size, void* d_ws, size_t ws_size,
                              hipStream_t stream) {
  const float* x = (const float*)d_in[0];
  const int* srcp = (const int*)d_in[1];
  const int* dstp = (const int*)d_in[2];
  const float* Wl[3]  = {(const float*)d_in[3], (const float*)d_in[6], (const float*)d_in[9]};
  const float* alp[3] = {(const float*)d_in[4], (const float*)d_in[7], (const float*)d_in[10]};
  const float* arl[3] = {(const float*)d_in[5], (const float*)d_in[8], (const float*)d_in[11]};
  float* out = (float*)d_out;
  (void)in_sizes; (void)n_in; (void)out_size;

  auto rup = [](size_t b) { return (b + 255) & ~(size_t)255; };
  size_t need = 3 * rup((size_t)NNODES * FDIM * 2) +        // b0, b1, fbuf
                2 * rup((size_t)NNODES * NH * 2) +          // el, er (bf16)
                rup((size_t)NREL * FDIM * FDIM * 2) +       // Wt (all 4 relations)
                2 * rup((size_t)NREL * NNODES * 4) +        // deg, ptrf
                rup((size_t)NREL * NEDGE * 4);              // csrc
  if (ws_size < need) return;  // diagnostic: zeros out, no crash

  char* ws = (char*)d_ws;
  size_t off = 0;
  auto alloc = [&](size_t bytes) -> void* { void* p = ws + off; off += rup(bytes); return p; };
  __bf16* b0   = (__bf16*)alloc((size_t)NNODES * FDIM * 2);
  __bf16* b1   = (__bf16*)alloc((size_t)NNODES * FDIM * 2);
  __bf16* fbuf = (__bf16*)alloc((size_t)NNODES * FDIM * 2);
  __bf16* el   = (__bf16*)alloc((size_t)NNODES * NH * 2);
  __bf16* er   = (__bf16*)alloc((size_t)NNODES * NH * 2);
  __bf16* Wt   = (__bf16*)alloc((size_t)NREL * FDIM * FDIM * 2);
  int* deg  = (int*)alloc((size_t)NREL * NNODES * 4);
  int* ptrf = (int*)alloc((size_t)NREL * NNODES * 4);
  int* csrc = (int*)alloc((size_t)NREL * NEDGE * 4);
  // cur + bsum alias into fbuf (dead during CSR build)
  int* cur  = (int*)fbuf;
  int* bsum = (int*)((char*)fbuf + rup((size_t)NREL * NNODES * 4));

  // ---- CSR by dst ----
  hipMemsetAsync(deg, 0, (size_t)NREL * NNODES * 4, stream);
  hipMemsetAsync(cur, 0, (size_t)NREL * NNODES * 4, stream);
  k_count<<<dim3((NEDGE + 255) / 256, NREL), 256, 0, stream>>>(dstp, deg);
  int ntot = NREL * NNODES;
  int nb1 = (ntot + 1023) / 1024;
  k_scan_a<<<nb1, 256, 0, stream>>>(deg, ptrf, bsum, ntot);
  k_scan_b<<<1, 256, 0, stream>>>(bsum, nb1);
  k_scan_c<<<(ntot + 255) / 256, 256, 0, stream>>>(ptrf, bsum, ntot);
  k_scatter<<<dim3((NEDGE + 255) / 256, NREL), 256, 0, stream>>>(srcp, dstp, ptrf, cur, csrc);

  // layer-0 input: conv x -> b1 as [N,256] bf16
  k_conv<<<(NNODES * 256) / 1024, 256, 0, stream>>>(x, b1);

  int ngrid = NMB * 4;  // 3128 (128x128 tiles over [100000, 512])
  for (int L = 0; L < 3; L++) {
    int K = (L == 0) ? 256 : FDIM;
    const __bf16* inb = (L == 1) ? b0 : b1;  // L0:b1(x), L1:b0, L2:b1
    __bf16* outb = (L == 0) ? b0 : b1;       // L2 writes d_out instead
    k_transW<<<dim3(K / 32, 16, NREL), dim3(32, 8), 0, stream>>>(Wl[L], Wt, K);
    for (int r = 0; r < NREL; r++) {
      k_gemm<<<ngrid, 256, 0, stream>>>(inb, Wt + (size_t)r * FDIM * K, fbuf,
                                        alp[L] + (size_t)r * 512,
                                        arl[L] + (size_t)r * 512,
                                        el, er, NNODES, K);
      if (L < 2)
        k_agg<<<NNODES / 4, 256, 0, stream>>>(fbuf, el, er, ptrf + (size_t)r * NNODES,
                                              deg + (size_t)r * NNODES, csrc, outb,
                                              r == 0 ? 1 : 0);
      else
        k_aggm<<<NNODES / 4, 256, 0, stream>>>(fbuf, el, er, ptrf + (size_t)r * NNODES,
                                               deg + (size_t)r * NNODES, csrc, out,
                                               r == 0 ? 1 : 0);
    }
  }
}